// Round 7
// baseline (424.915 us; speedup 1.0000x reference)
//
#include <hip/hip_runtime.h>
#include <hip/hip_bf16.h>

// B=128, T=512, I=128, H=256, O=1 (fp32 in/out)
// R7: split xp back out (R6 became DS-throughput-bound; the fused x-path was
// 35% of the per-step DS traffic).
//   Kernel A (xp v2): xp' = S*(W_ih·x + b_ih + b_hh), fp32, [B][T][H].
//     D[n][m] MFMA layout (A=W_ih resident, B=x rows) -> float4 stores.
//     256 blocks x 4 waves, 16 m-tiles/block, distance-2 prefetch, no LDS.
//   Kernel B (rnn v7) = R6 minus x-path: per step: seed acc from prefetched
//     xp' (bias+scale prefolded), 8 h ds_reads, 16 MFMA (4+4 split chains),
//     tanh epilogue, h-write, BAR. DS/CU-step: 120 -> 72 accesses.
//   v = S*(xp_raw + W_hh·h) = xp' + (S*W_hh)·h ; h = 1 - 2*rcp(exp2(v)+1).

#define B_ 128
#define T_ 512
#define I_ 128
#define H_ 256
#define SCALE 2.8853900817779268f   // 2*log2(e)

typedef __attribute__((ext_vector_type(8))) short short8;
typedef __attribute__((ext_vector_type(4))) float floatx4;

__device__ __forceinline__ short8 pack8(float4 lo, float4 hi) {
    __hip_bfloat162 p0 = __float22bfloat162_rn(float2{lo.x, lo.y});
    __hip_bfloat162 p1 = __float22bfloat162_rn(float2{lo.z, lo.w});
    __hip_bfloat162 p2 = __float22bfloat162_rn(float2{hi.x, hi.y});
    __hip_bfloat162 p3 = __float22bfloat162_rn(float2{hi.z, hi.w});
    int4 i;
    i.x = *(int*)&p0; i.y = *(int*)&p1; i.z = *(int*)&p2; i.w = *(int*)&p3;
    return *(short8*)&i;
}
__device__ __forceinline__ short8 pack8s(float4 lo, float4 hi, float s) {
    lo.x *= s; lo.y *= s; lo.z *= s; lo.w *= s;
    hi.x *= s; hi.y *= s; hi.z *= s; hi.w *= s;
    return pack8(lo, hi);
}
// tanh(z) where v = 2*log2e*z (prescaled). Builtins, not asm (R3 lesson).
__device__ __forceinline__ float tanh_s(float v) {
    float e = __builtin_amdgcn_exp2f(v);          // 2^v = exp(2z)
    float r = __builtin_amdgcn_rcpf(e + 1.0f);
    return __builtin_fmaf(-2.0f, r, 1.0f);        // 1 - 2/(e+1)
}

// ---------------- Kernel A: xp'[m][n] = S*(W_ih·x + b), m = b*T + t.
// D[n][m]: A-frag = W_ih rows (n), B-frag = x rows (m). Lane (l15,quad):
// D col=l15=m, row=quad*4+r=n -> store float4 at xp[(m0+l15)*H + n0+mtt*16+quad*4].
#define XP_GRID 256
#define XP_NT   ((B_ * T_ / 16) / XP_GRID)   // 16 m-tiles per block
__global__ __launch_bounds__(256, 1)
void xp_kernel(const float* __restrict__ x, const float* __restrict__ W_ih,
               const float* __restrict__ b_ih, const float* __restrict__ b_hh,
               float* __restrict__ xp) {
    const int tid  = threadIdx.x;
    const int wave = tid >> 6, lane = tid & 63;
    const int l15  = lane & 15, quad = lane >> 4;
    const int n0   = wave * 64;

    // resident W_ih' fragments (prescaled): 4 mtt x 4 kq
    short8 wfrag[4][4];
#pragma unroll
    for (int mtt = 0; mtt < 4; ++mtt)
#pragma unroll
        for (int kq = 0; kq < 4; ++kq) {
            const float* p = W_ih + (long)(n0 + mtt * 16 + l15) * I_ + kq * 32 + quad * 8;
            wfrag[mtt][kq] = pack8s(*(const float4*)p, *(const float4*)(p + 4), SCALE);
        }
    floatx4 biasv[4];
#pragma unroll
    for (int mtt = 0; mtt < 4; ++mtt)
#pragma unroll
        for (int r = 0; r < 4; ++r) {
            int n = n0 + mtt * 16 + quad * 4 + r;
            biasv[mtt][r] = SCALE * (b_ih[n] + b_hh[n]);
        }

    const long mbase = (long)blockIdx.x * XP_NT * 16;   // chunked: contiguous rows/block

    float4 qa[4][2], qb[4][2];
#define LDX(Q, IT)                                                              \
    {                                                                           \
        const int itc = ((IT) < XP_NT) ? (IT) : (XP_NT - 1);                    \
        const float* p = x + (mbase + (long)itc * 16 + l15) * I_ + quad * 8;    \
        _Pragma("unroll")                                                       \
        for (int kq = 0; kq < 4; ++kq) {                                        \
            Q[kq][0] = *(const float4*)(p + kq * 32);                           \
            Q[kq][1] = *(const float4*)(p + kq * 32 + 4);                       \
        }                                                                       \
    }
#define ITER(Q, IT, ILD)                                                        \
    {                                                                           \
        short8 xf[4];                                                           \
        _Pragma("unroll")                                                       \
        for (int kq = 0; kq < 4; ++kq) xf[kq] = pack8(Q[kq][0], Q[kq][1]);      \
        LDX(Q, ILD);                                                            \
        floatx4 acc[4];                                                         \
        _Pragma("unroll")                                                       \
        for (int mtt = 0; mtt < 4; ++mtt) acc[mtt] = biasv[mtt];                \
        _Pragma("unroll")                                                       \
        for (int kq = 0; kq < 4; ++kq)                                          \
            _Pragma("unroll")                                                   \
            for (int mtt = 0; mtt < 4; ++mtt)                                   \
                acc[mtt] = __builtin_amdgcn_mfma_f32_16x16x32_bf16(             \
                    wfrag[mtt][kq], xf[kq], acc[mtt], 0, 0, 0);                 \
        float* o = xp + (mbase + (long)(IT) * 16 + l15) * H_ + n0 + quad * 4;   \
        _Pragma("unroll")                                                       \
        for (int mtt = 0; mtt < 4; ++mtt) {                                     \
            float4 st = {acc[mtt][0], acc[mtt][1], acc[mtt][2], acc[mtt][3]};   \
            *(float4*)(o + mtt * 16) = st;                                      \
        }                                                                       \
    }

    LDX(qa, 0);
    LDX(qb, 1);
#pragma unroll 1
    for (int it = 0; it < XP_NT; it += 2) {
        ITER(qa, it, it + 2);
        ITER(qb, it + 1, it + 3);
    }
#undef ITER
#undef LDX
}

// ---------------- Kernel B: MFMA recurrence, 8 blocks x 16 batches, 8 waves.
// Per step: seed acc from xp' (prefetched 2 ahead) | 8 h ds_reads |
// 16 MFMA as 4 independent depth-4 chains | tanh+pack+h-write | BAR.
__global__ __launch_bounds__(512, 2)
void rnn_kernel(const float* __restrict__ xp, const float* __restrict__ W_hh,
                const float* __restrict__ W_fc, const float* __restrict__ b_fc,
                float* __restrict__ out) {
    __shared__ __align__(16) short hbuf[2][16][256];   // h_t bf16, 16B-XOR swizzled
    const int tid  = threadIdx.x;
    const int wave = tid >> 6, lane = tid & 63;
    const int l15  = lane & 15, quad = lane >> 4;
    const int b0   = blockIdx.x * 16;
    const int n0   = wave * 32;
    const int swz  = l15 & 7;

    // resident W_hh' fragments (prescaled)
    short8 wfrag[2][8];
#pragma unroll
    for (int mt = 0; mt < 2; ++mt)
#pragma unroll
        for (int kq = 0; kq < 8; ++kq) {
            const float* p = W_hh + (long)(n0 + mt * 16 + l15) * H_ + kq * 32 + quad * 8;
            wfrag[mt][kq] = pack8s(*(const float4*)p, *(const float4*)(p + 4), SCALE);
        }

    // zero hbuf[0] (h_0 = 0)
    {
        int* hz = (int*)&hbuf[0][0][0];
#pragma unroll
        for (int i = tid; i < 16 * 256 / 2; i += 512) hz[i] = 0;
    }

    // LDS offsets (shorts)
    int roff[8];
#pragma unroll
    for (int kq = 0; kq < 8; ++kq)
        roff[kq] = l15 * 256 + (((quad + 4 * kq) ^ swz) << 3);
    int woff[2];
#pragma unroll
    for (int mt = 0; mt < 2; ++mt) {
        int c = wave * 4 + 2 * mt + (quad >> 1);
        woff[mt] = l15 * 256 + ((c ^ swz) << 3) + (quad & 1) * 4;
    }

    // xp' prefetch: lane reads 2 float4 (mt=0 at +0, mt=1 at +16)
    const float* xpl = xp + (long)(b0 + l15) * T_ * H_ + n0 + quad * 4;
    float4 xvA0 = *(const float4*)(xpl);
    float4 xvA1 = *(const float4*)(xpl + 16);
    float4 xvB0 = *(const float4*)(xpl + H_);
    float4 xvB1 = *(const float4*)(xpl + H_ + 16);

    __syncthreads();   // hbuf zero visible

    const short* hb0r = &hbuf[0][0][0]; short* hb0w = &hbuf[0][0][0];
    const short* hb1r = &hbuf[1][0][0]; short* hb1w = &hbuf[1][0][0];

#define BAR() asm volatile("s_waitcnt lgkmcnt(0)\n\ts_barrier" ::: "memory")

#define STEP(HR, HW, XV0, XV1, TLD)                                             \
    {                                                                           \
        /* 1. h-fragment reads first: ds latency is the critical path */        \
        short8 hfrag[8];                                                        \
        _Pragma("unroll")                                                       \
        for (int kq = 0; kq < 8; ++kq)                                          \
            hfrag[kq] = *(const short8*)((HR) + roff[kq]);                      \
        /* 2. seed accumulators from xp' (bias+scale prefolded) */              \
        floatx4 aC[2], aZ[2];                                                   \
        aC[0] = (floatx4){XV0.x, XV0.y, XV0.z, XV0.w};                          \
        aC[1] = (floatx4){XV1.x, XV1.y, XV1.z, XV1.w};                          \
        aZ[0] = (floatx4){0.f, 0.f, 0.f, 0.f};                                  \
        aZ[1] = (floatx4){0.f, 0.f, 0.f, 0.f};                                  \
        /* 3. reload XV for t+2 (off critical path; BAR keeps vmcnt open) */    \
        XV0 = *(const float4*)(xpl + (long)(TLD) * H_);                         \
        XV1 = *(const float4*)(xpl + (long)(TLD) * H_ + 16);                    \
        /* 4. 16 h-MFMAs as 4 independent depth-4 chains */                     \
        _Pragma("unroll")                                                       \
        for (int kq = 0; kq < 4; ++kq)                                          \
            _Pragma("unroll")                                                   \
            for (int mt = 0; mt < 2; ++mt) {                                    \
                aC[mt] = __builtin_amdgcn_mfma_f32_16x16x32_bf16(               \
                    wfrag[mt][kq], hfrag[kq], aC[mt], 0, 0, 0);                 \
                aZ[mt] = __builtin_amdgcn_mfma_f32_16x16x32_bf16(               \
                    wfrag[mt][kq + 4], hfrag[kq + 4], aZ[mt], 0, 0, 0);         \
            }                                                                   \
        /* 5. merge + tanh + pack + h-write (critical path to barrier) */       \
        _Pragma("unroll")                                                       \
        for (int mt = 0; mt < 2; ++mt) {                                        \
            float r0 = tanh_s(aC[mt][0] + aZ[mt][0]);                           \
            float r1 = tanh_s(aC[mt][1] + aZ[mt][1]);                           \
            float r2 = tanh_s(aC[mt][2] + aZ[mt][2]);                           \
            float r3 = tanh_s(aC[mt][3] + aZ[mt][3]);                           \
            __hip_bfloat162 q01 = __float22bfloat162_rn(float2{r0, r1});        \
            __hip_bfloat162 q23 = __float22bfloat162_rn(float2{r2, r3});        \
            int2 wv; wv.x = *(int*)&q01; wv.y = *(int*)&q23;                    \
            *(int2*)((HW) + woff[mt]) = wv;                                     \
        }                                                                       \
        BAR();                                                                  \
    }

#pragma unroll 1
    for (int t = 0; t < T_; t += 2) {
        const int tl0 = (t + 2 < T_) ? t + 2 : T_ - 1;
        const int tl1 = (t + 3 < T_) ? t + 3 : T_ - 1;
        STEP(hb0r, hb1w, xvA0, xvA1, tl0);   // even t: read buf0, write buf1
        STEP(hb1r, hb0w, xvB0, xvB1, tl1);   // odd t:  read buf1, write buf0
    }
#undef STEP
#undef BAR

    // head: out[b] = sigmoid(b_fc + sum_n h_T[b][n] * W_fc[n]); h_T in hbuf[0]
    if (tid < 256) {
        const int bl = tid >> 4, seg = tid & 15;
        const int bswz = bl & 7;
        float p = 0.0f;
#pragma unroll
        for (int half = 0; half < 2; ++half) {
            const int c = 2 * seg + half;
            const short* hr = &hbuf[0][0][0] + bl * 256 + ((c ^ bswz) << 3);
#pragma unroll
            for (int i = 0; i < 8; ++i) {
                __hip_bfloat16 hv = *(const __hip_bfloat16*)(hr + i);
                p += __bfloat162float(hv) * W_fc[c * 8 + i];
            }
        }
#pragma unroll
        for (int off = 1; off < 16; off <<= 1) p += __shfl_xor(p, off);
        if (seg == 0) out[b0 + bl] = 1.0f / (1.0f + __expf(-(p + b_fc[0])));
    }
}

extern "C" void kernel_launch(void* const* d_in, const int* in_sizes, int n_in,
                              void* d_out, int out_size, void* d_ws, size_t ws_size,
                              hipStream_t stream) {
    const float* x    = (const float*)d_in[0];
    const float* W_ih = (const float*)d_in[1];
    const float* W_hh = (const float*)d_in[2];
    const float* b_ih = (const float*)d_in[3];
    const float* b_hh = (const float*)d_in[4];
    const float* W_fc = (const float*)d_in[5];
    const float* b_fc = (const float*)d_in[6];
    float* out = (float*)d_out;

    float* xp = (float*)d_ws;   // B*T*H fp32 = 67.1 MB (round-1-proven ws footprint)

    xp_kernel<<<XP_GRID, 256, 0, stream>>>(x, W_ih, b_ih, b_hh, xp);
    rnn_kernel<<<B_ / 16, 512, 0, stream>>>(xp, W_hh, W_fc, b_fc, out);
}

// Round 8
// 395.975 us; speedup vs baseline: 1.0731x; 1.0731x over previous
//
#include <hip/hip_runtime.h>
#include <hip/hip_bf16.h>

// B=128, T=512, I=128, H=256, O=1 (fp32 in/out)
// R8: int8 recurrence. R7 was DS-throughput-bound (64 b128 h-reads/CU-step =
// ~80% of the 1514-cy step; every wave must read all of h, b128 is max width).
// Only lever left: fewer bytes per K-element -> mfma_i32_16x16x64_i8 (K=64).
//   h stored int8 (scale 127; |tanh|<1 -> exact headroom)
//   W_hh int8 (scale 2032=127*16; |W|<=1/16 -> |q|<=127, no clamp needed)
//   i32 exact accumulate; v = (float)acc * SCALE/(127*2032) + xp' ; tanh via
//   exp2/rcp builtins (R3 lesson: builtins not asm for MFMA->VALU hazards).
// DS/CU-step: 64 -> 32 b128 reads. Kernel A (xp') unchanged from R7.

#define B_ 128
#define T_ 512
#define I_ 128
#define H_ 256
#define SCALE 2.8853900817779268f    // 2*log2(e)
#define WSC 2032.0f                  // W_hh int8 scale (127*16)
#define HSC 127.0f                   // h int8 scale
#define SCOMB (SCALE / (WSC * HSC))  // i32 acc -> prescaled preact

typedef __attribute__((ext_vector_type(8))) short short8;
typedef __attribute__((ext_vector_type(4))) float floatx4;
typedef __attribute__((ext_vector_type(4))) int int4v;

__device__ __forceinline__ short8 pack8(float4 lo, float4 hi) {
    __hip_bfloat162 p0 = __float22bfloat162_rn(float2{lo.x, lo.y});
    __hip_bfloat162 p1 = __float22bfloat162_rn(float2{lo.z, lo.w});
    __hip_bfloat162 p2 = __float22bfloat162_rn(float2{hi.x, hi.y});
    __hip_bfloat162 p3 = __float22bfloat162_rn(float2{hi.z, hi.w});
    int4 i;
    i.x = *(int*)&p0; i.y = *(int*)&p1; i.z = *(int*)&p2; i.w = *(int*)&p3;
    return *(short8*)&i;
}
__device__ __forceinline__ short8 pack8s(float4 lo, float4 hi, float s) {
    lo.x *= s; lo.y *= s; lo.z *= s; lo.w *= s;
    hi.x *= s; hi.y *= s; hi.z *= s; hi.w *= s;
    return pack8(lo, hi);
}
// tanh(z) where v = 2*log2e*z is the prescaled preact.
__device__ __forceinline__ float tanh_s(float v) {
    float e = __builtin_amdgcn_exp2f(v);          // 2^v = exp(2z)
    float r = __builtin_amdgcn_rcpf(e + 1.0f);
    return __builtin_fmaf(-2.0f, r, 1.0f);        // 1 - 2/(e+1)
}
// quantize 4 floats (|v*s| <= 127) -> packed int8 dword, RNE
__device__ __forceinline__ int q4(float a, float b, float c, float d, float s) {
    int qa = (int)rintf(a * s) & 255;
    int qb = (int)rintf(b * s) & 255;
    int qc = (int)rintf(c * s) & 255;
    int qd = (int)rintf(d * s) & 255;
    return qa | (qb << 8) | (qc << 16) | (qd << 24);
}

// ---------------- Kernel A: xp'[m][n] = S*(W_ih·x + b), m = b*T + t. (R7 proven)
#define XP_GRID 256
#define XP_NT   ((B_ * T_ / 16) / XP_GRID)   // 16 m-tiles per block
__global__ __launch_bounds__(256, 1)
void xp_kernel(const float* __restrict__ x, const float* __restrict__ W_ih,
               const float* __restrict__ b_ih, const float* __restrict__ b_hh,
               float* __restrict__ xp) {
    const int tid  = threadIdx.x;
    const int wave = tid >> 6, lane = tid & 63;
    const int l15  = lane & 15, quad = lane >> 4;
    const int n0   = wave * 64;

    short8 wfrag[4][4];
#pragma unroll
    for (int mtt = 0; mtt < 4; ++mtt)
#pragma unroll
        for (int kq = 0; kq < 4; ++kq) {
            const float* p = W_ih + (long)(n0 + mtt * 16 + l15) * I_ + kq * 32 + quad * 8;
            wfrag[mtt][kq] = pack8s(*(const float4*)p, *(const float4*)(p + 4), SCALE);
        }
    floatx4 biasv[4];
#pragma unroll
    for (int mtt = 0; mtt < 4; ++mtt)
#pragma unroll
        for (int r = 0; r < 4; ++r) {
            int n = n0 + mtt * 16 + quad * 4 + r;
            biasv[mtt][r] = SCALE * (b_ih[n] + b_hh[n]);
        }

    const long mbase = (long)blockIdx.x * XP_NT * 16;

    float4 qa[4][2], qb[4][2];
#define LDX(Q, IT)                                                              \
    {                                                                           \
        const int itc = ((IT) < XP_NT) ? (IT) : (XP_NT - 1);                    \
        const float* p = x + (mbase + (long)itc * 16 + l15) * I_ + quad * 8;    \
        _Pragma("unroll")                                                       \
        for (int kq = 0; kq < 4; ++kq) {                                        \
            Q[kq][0] = *(const float4*)(p + kq * 32);                           \
            Q[kq][1] = *(const float4*)(p + kq * 32 + 4);                       \
        }                                                                       \
    }
#define ITER(Q, IT, ILD)                                                        \
    {                                                                           \
        short8 xf[4];                                                           \
        _Pragma("unroll")                                                       \
        for (int kq = 0; kq < 4; ++kq) xf[kq] = pack8(Q[kq][0], Q[kq][1]);      \
        LDX(Q, ILD);                                                            \
        floatx4 acc[4];                                                         \
        _Pragma("unroll")                                                       \
        for (int mtt = 0; mtt < 4; ++mtt) acc[mtt] = biasv[mtt];                \
        _Pragma("unroll")                                                       \
        for (int kq = 0; kq < 4; ++kq)                                          \
            _Pragma("unroll")                                                   \
            for (int mtt = 0; mtt < 4; ++mtt)                                   \
                acc[mtt] = __builtin_amdgcn_mfma_f32_16x16x32_bf16(             \
                    wfrag[mtt][kq], xf[kq], acc[mtt], 0, 0, 0);                 \
        float* o = xp + (mbase + (long)(IT) * 16 + l15) * H_ + n0 + quad * 4;   \
        _Pragma("unroll")                                                       \
        for (int mtt = 0; mtt < 4; ++mtt) {                                     \
            float4 st = {acc[mtt][0], acc[mtt][1], acc[mtt][2], acc[mtt][3]};   \
            *(float4*)(o + mtt * 16) = st;                                      \
        }                                                                       \
    }

    LDX(qa, 0);
    LDX(qb, 1);
#pragma unroll 1
    for (int it = 0; it < XP_NT; it += 2) {
        ITER(qa, it, it + 2);
        ITER(qb, it + 1, it + 3);
    }
#undef ITER
#undef LDX
}

// ---------------- Kernel B: int8 MFMA recurrence, 8 blocks x 16 batches, 8 waves.
// h in LDS as int8 [buf][batch=16][256 B], 16B-block swizzle c' = c ^ (l15&7).
// Per step: 4 h ds_read_b128 | 8 MFMA i8 K=64 (2x depth-2 chains per mt) |
// epilogue f32 cvt+fma+tanh+quantize -> ds_write_b32 | BAR.
__global__ __launch_bounds__(512, 2)
void rnn_kernel(const float* __restrict__ xp, const float* __restrict__ W_hh,
                const float* __restrict__ W_fc, const float* __restrict__ b_fc,
                float* __restrict__ out) {
    __shared__ __align__(16) signed char hbuf[2][16][256];
    const int tid  = threadIdx.x;
    const int wave = tid >> 6, lane = tid & 63;
    const int l15  = lane & 15, quad = lane >> 4;
    const int b0   = blockIdx.x * 16;
    const int n0   = wave * 32;
    const int swz  = l15 & 7;

    // W_hh int8 A-fragments: [mt][kq], row n0+mt*16+l15, K-bytes kq*64+quad*16
    int4v wfrag[2][4];
#pragma unroll
    for (int mt = 0; mt < 2; ++mt)
#pragma unroll
        for (int kq = 0; kq < 4; ++kq) {
            const float* p = W_hh + (long)(n0 + mt * 16 + l15) * H_ + kq * 64 + quad * 16;
            int4v f;
#pragma unroll
            for (int j = 0; j < 4; ++j) {
                float4 w = *(const float4*)(p + j * 4);
                f[j] = q4(w.x, w.y, w.z, w.w, WSC);
            }
            wfrag[mt][kq] = f;
        }

    // zero hbuf[0] (h_0 = 0)
    {
        int* hz = (int*)&hbuf[0][0][0];
#pragma unroll
        for (int i = tid; i < 2 * 16 * 256 / 4; i += 512) hz[i] = 0;
    }

    // LDS offsets (bytes); 16 16B-blocks per 256B row
    int roff[4];
#pragma unroll
    for (int kq = 0; kq < 4; ++kq)
        roff[kq] = l15 * 256 + (((kq * 4 + quad) ^ swz) << 4);
    int woff[2];
#pragma unroll
    for (int mt = 0; mt < 2; ++mt) {
        int c = wave * 2 + mt;
        woff[mt] = l15 * 256 + ((c ^ swz) << 4) + quad * 4;
    }

    // xp' prefetch: lane holds 2 float4 (mt=0 at +0, mt=1 at +16)
    const float* xpl = xp + (long)(b0 + l15) * T_ * H_ + n0 + quad * 4;
    float4 xvA0 = *(const float4*)(xpl);
    float4 xvA1 = *(const float4*)(xpl + 16);
    float4 xvB0 = *(const float4*)(xpl + H_);
    float4 xvB1 = *(const float4*)(xpl + H_ + 16);

    __syncthreads();   // hbuf zero visible

    const signed char* hb0r = &hbuf[0][0][0]; signed char* hb0w = &hbuf[0][0][0];
    const signed char* hb1r = &hbuf[1][0][0]; signed char* hb1w = &hbuf[1][0][0];

#define BAR() asm volatile("s_waitcnt lgkmcnt(0)\n\ts_barrier" ::: "memory")

#define STEP(HR, HW, XV0, XV1, TLD)                                             \
    {                                                                           \
        /* 1. h-fragment reads (4 b128) — the critical-path latency */          \
        int4v hfrag[4];                                                         \
        _Pragma("unroll")                                                       \
        for (int kq = 0; kq < 4; ++kq)                                          \
            hfrag[kq] = *(const int4v*)((HR) + roff[kq]);                       \
        /* 2. save current xp', then reload for t+2 (vmcnt stays open) */       \
        float4 xc0 = XV0, xc1 = XV1;                                            \
        XV0 = *(const float4*)(xpl + (long)(TLD) * H_);                         \
        XV1 = *(const float4*)(xpl + (long)(TLD) * H_ + 16);                    \
        /* 3. 8 MFMAs: per mt, two depth-2 chains */                            \
        int4v aC[2], aZ[2];                                                     \
        _Pragma("unroll")                                                       \
        for (int mt = 0; mt < 2; ++mt) {                                        \
            aC[mt] = (int4v){0, 0, 0, 0};                                       \
            aZ[mt] = (int4v){0, 0, 0, 0};                                       \
        }                                                                       \
        _Pragma("unroll")                                                       \
        for (int mt = 0; mt < 2; ++mt) {                                        \
            aC[mt] = __builtin_amdgcn_mfma_i32_16x16x64_i8(                     \
                wfrag[mt][0], hfrag[0], aC[mt], 0, 0, 0);                       \
            aZ[mt] = __builtin_amdgcn_mfma_i32_16x16x64_i8(                     \
                wfrag[mt][2], hfrag[2], aZ[mt], 0, 0, 0);                       \
            aC[mt] = __builtin_amdgcn_mfma_i32_16x16x64_i8(                     \
                wfrag[mt][1], hfrag[1], aC[mt], 0, 0, 0);                       \
            aZ[mt] = __builtin_amdgcn_mfma_i32_16x16x64_i8(                     \
                wfrag[mt][3], hfrag[3], aZ[mt], 0, 0, 0);                       \
        }                                                                       \
        /* 4. epilogue: f32 = acc*SCOMB + xp', tanh, quantize, b32 write */     \
        _Pragma("unroll")                                                       \
        for (int mt = 0; mt < 2; ++mt) {                                        \
            float4 xc = (mt == 0) ? xc0 : xc1;                                  \
            float r0 = tanh_s(__builtin_fmaf((float)(aC[mt][0] + aZ[mt][0]), SCOMB, xc.x)); \
            float r1 = tanh_s(__builtin_fmaf((float)(aC[mt][1] + aZ[mt][1]), SCOMB, xc.y)); \
            float r2 = tanh_s(__builtin_fmaf((float)(aC[mt][2] + aZ[mt][2]), SCOMB, xc.z)); \
            float r3 = tanh_s(__builtin_fmaf((float)(aC[mt][3] + aZ[mt][3]), SCOMB, xc.w)); \
            *(int*)((HW) + woff[mt]) = q4(r0, r1, r2, r3, HSC);                 \
        }                                                                       \
        BAR();                                                                  \
    }

#pragma unroll 1
    for (int t = 0; t < T_; t += 2) {
        const int tl0 = (t + 2 < T_) ? t + 2 : T_ - 1;
        const int tl1 = (t + 3 < T_) ? t + 3 : T_ - 1;
        STEP(hb0r, hb1w, xvA0, xvA1, tl0);   // even t: read buf0, write buf1
        STEP(hb1r, hb0w, xvB0, xvB1, tl1);   // odd t:  read buf1, write buf0
    }
#undef STEP
#undef BAR

    // head: out[b] = sigmoid(b_fc + (1/HSC)*sum_n hq[b][n]*W_fc[n]); h_T in hbuf[0]
    if (tid < 256) {
        const int bl = tid >> 4, seg = tid & 15;
        const int bswz = bl & 7;
        const signed char* hr = &hbuf[0][0][0] + bl * 256 + ((seg ^ bswz) << 4);
        float p = 0.0f;
#pragma unroll
        for (int i = 0; i < 16; ++i)
            p += (float)hr[i] * W_fc[seg * 16 + i];
#pragma unroll
        for (int off = 1; off < 16; off <<= 1) p += __shfl_xor(p, off);
        if (seg == 0)
            out[b0 + bl] = 1.0f / (1.0f + __expf(-(p * (1.0f / HSC) + b_fc[0])));
    }
}

extern "C" void kernel_launch(void* const* d_in, const int* in_sizes, int n_in,
                              void* d_out, int out_size, void* d_ws, size_t ws_size,
                              hipStream_t stream) {
    const float* x    = (const float*)d_in[0];
    const float* W_ih = (const float*)d_in[1];
    const float* W_hh = (const float*)d_in[2];
    const float* b_ih = (const float*)d_in[3];
    const float* b_hh = (const float*)d_in[4];
    const float* W_fc = (const float*)d_in[5];
    const float* b_fc = (const float*)d_in[6];
    float* out = (float*)d_out;

    float* xp = (float*)d_ws;   // B*T*H fp32 = 67.1 MB

    xp_kernel<<<XP_GRID, 256, 0, stream>>>(x, W_ih, b_ih, b_hh, xp);
    rnn_kernel<<<B_ / 16, 512, 0, stream>>>(xp, W_hh, W_fc, b_fc, out);
}

// Round 9
// 357.671 us; speedup vs baseline: 1.1880x; 1.1071x over previous
//
#include <hip/hip_runtime.h>
#include <hip/hip_bf16.h>

// B=128, T=512, I=128, H=256, O=1 (fp32 in/out)
// R9: epilogue-minimal int8 recurrence. R8 became VALU-bound (epilogue ~12.5
// ops/elem, VALUBusy 67% of active CUs). Changes:
//   * xp kernel outputs xq = rint((W_ih·x+b)*WSC*HSC) as int32 -> rnn seeds
//     the i8 MFMA accumulator directly (kills per-elem xp-fma + acc merge;
//     single depth-4 MFMA chain per mt). |acc| < 5.2M << 2^31, f32-exact.
//   * tanh-finish + quantize folded into ONE fma: q = 127 - 254*rcp;
//     pk = fma(-254, rcp, 2^23+2^22+127) -> RNE int8 in low mantissa byte.
//   * byte-gather via v_perm_b32 (3 perms / 4 elems).
// Epilogue: 6 VALU/elem (2 trans) vs 12.5. DS unchanged (4 b128 reads/wave).

#define B_ 128
#define T_ 512
#define I_ 128
#define H_ 256
#define SCALE 2.8853900817779268f    // 2*log2(e)
#define WSC 2032.0f                  // W_hh int8 scale (127*16; |W|<=1/16 exact)
#define HSC 127.0f                   // h int8 scale
#define WHS (WSC * HSC)              // 258064: xp pre-quant scale
#define SCOMB (SCALE / WHS)          // i32 acc -> prescaled preact
#define MAGICQ 12583039.0f           // 2^23 + 2^22 + 127

typedef __attribute__((ext_vector_type(8))) short short8;
typedef __attribute__((ext_vector_type(4))) float floatx4;
typedef __attribute__((ext_vector_type(4))) int int4v;

__device__ __forceinline__ short8 pack8(float4 lo, float4 hi) {
    __hip_bfloat162 p0 = __float22bfloat162_rn(float2{lo.x, lo.y});
    __hip_bfloat162 p1 = __float22bfloat162_rn(float2{lo.z, lo.w});
    __hip_bfloat162 p2 = __float22bfloat162_rn(float2{hi.x, hi.y});
    __hip_bfloat162 p3 = __float22bfloat162_rn(float2{hi.z, hi.w});
    int4 i;
    i.x = *(int*)&p0; i.y = *(int*)&p1; i.z = *(int*)&p2; i.w = *(int*)&p3;
    return *(short8*)&i;
}
// quantize 4 floats (|v*s| <= 127) -> packed int8 dword, RNE (W_hh setup only)
__device__ __forceinline__ int q4(float a, float b, float c, float d, float s) {
    int qa = (int)rintf(a * s) & 255;
    int qb = (int)rintf(b * s) & 255;
    int qc = (int)rintf(c * s) & 255;
    int qd = (int)rintf(d * s) & 255;
    return qa | (qb << 8) | (qc << 16) | (qd << 24);
}

// ---------------- Kernel A: xq[m][n] = rint((W_ih·x + b) * WHS), int32.
// m = b*T + t. D[n][m] MFMA layout (A=W_ih bf16 resident, B=x rows).
#define XP_GRID 256
#define XP_NT   ((B_ * T_ / 16) / XP_GRID)   // 16 m-tiles per block
__global__ __launch_bounds__(256, 1)
void xp_kernel(const float* __restrict__ x, const float* __restrict__ W_ih,
               const float* __restrict__ b_ih, const float* __restrict__ b_hh,
               int* __restrict__ xq) {
    const int tid  = threadIdx.x;
    const int wave = tid >> 6, lane = tid & 63;
    const int l15  = lane & 15, quad = lane >> 4;
    const int n0   = wave * 64;

    short8 wfrag[4][4];   // plain bf16 (no prescale; quantization happens at store)
#pragma unroll
    for (int mtt = 0; mtt < 4; ++mtt)
#pragma unroll
        for (int kq = 0; kq < 4; ++kq) {
            const float* p = W_ih + (long)(n0 + mtt * 16 + l15) * I_ + kq * 32 + quad * 8;
            wfrag[mtt][kq] = pack8(*(const float4*)p, *(const float4*)(p + 4));
        }
    floatx4 biasv[4];
#pragma unroll
    for (int mtt = 0; mtt < 4; ++mtt)
#pragma unroll
        for (int r = 0; r < 4; ++r) {
            int n = n0 + mtt * 16 + quad * 4 + r;
            biasv[mtt][r] = b_ih[n] + b_hh[n];
        }

    const long mbase = (long)blockIdx.x * XP_NT * 16;

    float4 qa[4][2], qb[4][2];
#define LDX(Q, IT)                                                              \
    {                                                                           \
        const int itc = ((IT) < XP_NT) ? (IT) : (XP_NT - 1);                    \
        const float* p = x + (mbase + (long)itc * 16 + l15) * I_ + quad * 8;    \
        _Pragma("unroll")                                                       \
        for (int kq = 0; kq < 4; ++kq) {                                        \
            Q[kq][0] = *(const float4*)(p + kq * 32);                           \
            Q[kq][1] = *(const float4*)(p + kq * 32 + 4);                       \
        }                                                                       \
    }
#define ITER(Q, IT, ILD)                                                        \
    {                                                                           \
        short8 xf[4];                                                           \
        _Pragma("unroll")                                                       \
        for (int kq = 0; kq < 4; ++kq) xf[kq] = pack8(Q[kq][0], Q[kq][1]);      \
        LDX(Q, ILD);                                                            \
        floatx4 acc[4];                                                         \
        _Pragma("unroll")                                                       \
        for (int mtt = 0; mtt < 4; ++mtt) acc[mtt] = biasv[mtt];                \
        _Pragma("unroll")                                                       \
        for (int kq = 0; kq < 4; ++kq)                                          \
            _Pragma("unroll")                                                   \
            for (int mtt = 0; mtt < 4; ++mtt)                                   \
                acc[mtt] = __builtin_amdgcn_mfma_f32_16x16x32_bf16(             \
                    wfrag[mtt][kq], xf[kq], acc[mtt], 0, 0, 0);                 \
        int* o = xq + (mbase + (long)(IT) * 16 + l15) * H_ + n0 + quad * 4;     \
        _Pragma("unroll")                                                       \
        for (int mtt = 0; mtt < 4; ++mtt) {                                     \
            int4 st;                                                            \
            st.x = (int)rintf(acc[mtt][0] * WHS);                               \
            st.y = (int)rintf(acc[mtt][1] * WHS);                               \
            st.z = (int)rintf(acc[mtt][2] * WHS);                               \
            st.w = (int)rintf(acc[mtt][3] * WHS);                               \
            *(int4*)(o + mtt * 16) = st;                                        \
        }                                                                       \
    }

    LDX(qa, 0);
    LDX(qb, 1);
#pragma unroll 1
    for (int it = 0; it < XP_NT; it += 2) {
        ITER(qa, it, it + 2);
        ITER(qb, it + 1, it + 3);
    }
#undef ITER
#undef LDX
}

// ---------------- Kernel B: int8 MFMA recurrence, 8 blocks x 16 batches, 8 waves.
// Per step: 4 h ds_read_b128 | seed acc = xq (int32, prefetched 2 ahead) |
// 8 MFMA i8 K=64 (depth-4 chain per mt) | epilogue 6 VALU/elem + perm-pack |
// ds_write_b32 | BAR.
__global__ __launch_bounds__(512, 2)
void rnn_kernel(const int* __restrict__ xq, const float* __restrict__ W_hh,
                const float* __restrict__ W_fc, const float* __restrict__ b_fc,
                float* __restrict__ out) {
    __shared__ __align__(16) signed char hbuf[2][16][256];
    const int tid  = threadIdx.x;
    const int wave = tid >> 6, lane = tid & 63;
    const int l15  = lane & 15, quad = lane >> 4;
    const int b0   = blockIdx.x * 16;
    const int n0   = wave * 32;
    const int swz  = l15 & 7;

    // W_hh int8 A-fragments: [mt][kq], row n0+mt*16+l15, K-bytes kq*64+quad*16
    int4v wfrag[2][4];
#pragma unroll
    for (int mt = 0; mt < 2; ++mt)
#pragma unroll
        for (int kq = 0; kq < 4; ++kq) {
            const float* p = W_hh + (long)(n0 + mt * 16 + l15) * H_ + kq * 64 + quad * 16;
            int4v f;
#pragma unroll
            for (int j = 0; j < 4; ++j) {
                float4 w = *(const float4*)(p + j * 4);
                f[j] = q4(w.x, w.y, w.z, w.w, WSC);
            }
            wfrag[mt][kq] = f;
        }

    // zero hbuf[0] (h_0 = 0)
    {
        int* hz = (int*)&hbuf[0][0][0];
#pragma unroll
        for (int i = tid; i < 2 * 16 * 256 / 4; i += 512) hz[i] = 0;
    }

    // LDS offsets (bytes); 16 16B-blocks per 256B row
    int roff[4];
#pragma unroll
    for (int kq = 0; kq < 4; ++kq)
        roff[kq] = l15 * 256 + (((kq * 4 + quad) ^ swz) << 4);
    int woff[2];
#pragma unroll
    for (int mt = 0; mt < 2; ++mt) {
        int c = wave * 2 + mt;
        woff[mt] = l15 * 256 + ((c ^ swz) << 4) + quad * 4;
    }

    // xq prefetch: lane holds 2 int4 (mt=0 at +0, mt=1 at +16)
    const int* xql = xq + (long)(b0 + l15) * T_ * H_ + n0 + quad * 4;
    int4v xvA0 = *(const int4v*)(xql);
    int4v xvA1 = *(const int4v*)(xql + 16);
    int4v xvB0 = *(const int4v*)(xql + H_);
    int4v xvB1 = *(const int4v*)(xql + H_ + 16);

    __syncthreads();   // hbuf zero visible

    const signed char* hb0r = &hbuf[0][0][0]; signed char* hb0w = &hbuf[0][0][0];
    const signed char* hb1r = &hbuf[1][0][0]; signed char* hb1w = &hbuf[1][0][0];

#define BAR() asm volatile("s_waitcnt lgkmcnt(0)\n\ts_barrier" ::: "memory")

// per-element: cvt, mul, exp2, add, rcp, fma(-254,rc,MAGICQ) -> int8 in low byte
#define TQ(ACCI)                                                                \
    ({                                                                          \
        float v_ = (float)(ACCI) * SCOMB;                                       \
        float e_ = __builtin_amdgcn_exp2f(v_);                                  \
        float rc_ = __builtin_amdgcn_rcpf(e_ + 1.0f);                           \
        __builtin_fmaf(-254.0f, rc_, MAGICQ);                                   \
    })

#define STEP(HR, HW, XV0, XV1, TLD)                                             \
    {                                                                           \
        /* 1. h-fragment reads (4 b128) — critical-path latency */              \
        int4v hfrag[4];                                                         \
        _Pragma("unroll")                                                       \
        for (int kq = 0; kq < 4; ++kq)                                          \
            hfrag[kq] = *(const int4v*)((HR) + roff[kq]);                       \
        /* 2. seed accumulators from xq; reload XV for t+2 */                   \
        int4v aC[2];                                                            \
        aC[0] = XV0; aC[1] = XV1;                                               \
        XV0 = *(const int4v*)(xql + (long)(TLD) * H_);                          \
        XV1 = *(const int4v*)(xql + (long)(TLD) * H_ + 16);                     \
        /* 3. 8 MFMAs: depth-4 chain per mt (2 independent chains) */           \
        _Pragma("unroll")                                                       \
        for (int kq = 0; kq < 4; ++kq)                                          \
            _Pragma("unroll")                                                   \
            for (int mt = 0; mt < 2; ++mt)                                      \
                aC[mt] = __builtin_amdgcn_mfma_i32_16x16x64_i8(                 \
                    wfrag[mt][kq], hfrag[kq], aC[mt], 0, 0, 0);                 \
        /* 4. epilogue: tanh+quantize fused, perm byte-gather, b32 write */     \
        _Pragma("unroll")                                                       \
        for (int mt = 0; mt < 2; ++mt) {                                        \
            float f0 = TQ(aC[mt][0]);                                           \
            float f1 = TQ(aC[mt][1]);                                           \
            float f2 = TQ(aC[mt][2]);                                           \
            float f3 = TQ(aC[mt][3]);                                           \
            unsigned t01 = __builtin_amdgcn_perm(*(unsigned*)&f1, *(unsigned*)&f0, 0x00000400u); \
            unsigned t23 = __builtin_amdgcn_perm(*(unsigned*)&f3, *(unsigned*)&f2, 0x00000400u); \
            unsigned pk  = __builtin_amdgcn_perm(t23, t01, 0x05040100u);        \
            *(int*)((HW) + woff[mt]) = (int)pk;                                 \
        }                                                                       \
        BAR();                                                                  \
    }

#pragma unroll 1
    for (int t = 0; t < T_; t += 2) {
        const int tl0 = (t + 2 < T_) ? t + 2 : T_ - 1;
        const int tl1 = (t + 3 < T_) ? t + 3 : T_ - 1;
        STEP(hb0r, hb1w, xvA0, xvA1, tl0);   // even t: read buf0, write buf1
        STEP(hb1r, hb0w, xvB0, xvB1, tl1);   // odd t:  read buf1, write buf0
    }
#undef STEP
#undef TQ
#undef BAR

    // head: out[b] = sigmoid(b_fc + (1/HSC)*sum_n hq[b][n]*W_fc[n]); h_T in hbuf[0]
    if (tid < 256) {
        const int bl = tid >> 4, seg = tid & 15;
        const int bswz = bl & 7;
        const signed char* hr = &hbuf[0][0][0] + bl * 256 + ((seg ^ bswz) << 4);
        float p = 0.0f;
#pragma unroll
        for (int i = 0; i < 16; ++i)
            p += (float)hr[i] * W_fc[seg * 16 + i];
#pragma unroll
        for (int off = 1; off < 16; off <<= 1) p += __shfl_xor(p, off);
        if (seg == 0)
            out[b0 + bl] = 1.0f / (1.0f + __expf(-(p * (1.0f / HSC) + b_fc[0])));
    }
}

extern "C" void kernel_launch(void* const* d_in, const int* in_sizes, int n_in,
                              void* d_out, int out_size, void* d_ws, size_t ws_size,
                              hipStream_t stream) {
    const float* x    = (const float*)d_in[0];
    const float* W_ih = (const float*)d_in[1];
    const float* W_hh = (const float*)d_in[2];
    const float* b_ih = (const float*)d_in[3];
    const float* b_hh = (const float*)d_in[4];
    const float* W_fc = (const float*)d_in[5];
    const float* b_fc = (const float*)d_in[6];
    float* out = (float*)d_out;

    int* xq = (int*)d_ws;   // B*T*H int32 = 67.1 MB

    xp_kernel<<<XP_GRID, 256, 0, stream>>>(x, W_ih, b_ih, b_hh, xq);
    rnn_kernel<<<B_ / 16, 512, 0, stream>>>(xq, W_hh, W_fc, b_fc, out);
}

// Round 12
// 351.875 us; speedup vs baseline: 1.2076x; 1.0165x over previous
//
#include <hip/hip_runtime.h>
#include <hip/hip_bf16.h>

// B=128, T=512, I=128, H=256, O=1 (fp32 in/out)
// R10b (second resubmit; two broker failures, no kernel signal — source
// hygiene tweaks only, zero behavioral change).
// LUT epilogue. R9 was trans-issue-bound (16 exp2/rcp per wave-step ~ 510
// cy/SIMD of the 1209-cy step). h is int8-quantized, so tanh∘quantize has 255
// outputs -> 8192-entry int8 LDS LUT over prescaled v in [-16,16], d=1/256
// (cell err 0.09 quantum ~ exact). Per elem: cvt, fma, clamp, magic-add, and,
// ds_read_i8, perm-pack = 5 VALU + 1 DS, 0 trans.
//   * xq (int32 pre-quantized xp) seeds the i8 MFMA accumulator (R9).
//   * W_hh int8 (scale 2032), h int8 (scale 127), i32 exact accumulate (R8).
//   * 8 waves x mt=2, XOR-swizzled LDS, one raw BAR per step (R2/R6).

#define B_ 128
#define T_ 512
#define I_ 128
#define H_ 256
#define SCALE 2.8853900817779268f    // 2*log2(e)
#define WSC 2032.0f                  // W_hh int8 scale (127*16; |W|<=1/16 exact)
#define HSC 127.0f                   // h int8 scale
#define WHS (WSC * HSC)              // 258064: xp pre-quant scale
#define K1F (SCALE * 256.0f / WHS)   // i32 acc -> LUT index units (v * 256)
#define MAGICA 12582912.0f           // 2^23 + 2^22 (mantissa-int trick)

typedef __attribute__((ext_vector_type(8))) short short8;
typedef __attribute__((ext_vector_type(4))) float floatx4;
typedef __attribute__((ext_vector_type(4))) int int4v;

__device__ __forceinline__ short8 pack8(float4 lo, float4 hi) {
    __hip_bfloat162 p0 = __float22bfloat162_rn(float2{lo.x, lo.y});
    __hip_bfloat162 p1 = __float22bfloat162_rn(float2{lo.z, lo.w});
    __hip_bfloat162 p2 = __float22bfloat162_rn(float2{hi.x, hi.y});
    __hip_bfloat162 p3 = __float22bfloat162_rn(float2{hi.z, hi.w});
    int4 i;
    i.x = *(int*)&p0; i.y = *(int*)&p1; i.z = *(int*)&p2; i.w = *(int*)&p3;
    return *(short8*)&i;
}
// quantize 4 floats (|v*s| <= 127) -> packed int8 dword, RNE (W_hh setup only)
__device__ __forceinline__ int q4(float a, float b, float c, float d, float s) {
    int qa = (int)rintf(a * s) & 255;
    int qb = (int)rintf(b * s) & 255;
    int qc = (int)rintf(c * s) & 255;
    int qd = (int)rintf(d * s) & 255;
    return qa | (qb << 8) | (qc << 16) | (qd << 24);
}
// i32 acc -> LUT index: t = clamp(acc*K1F + 4096, 0, 8191); idx = rint(t)
__device__ __forceinline__ int lut_idx(int acci) {
    float t = __builtin_fmaf((float)acci, K1F, 4096.0f);
    t = fminf(fmaxf(t, 0.0f), 8191.0f);
    return __float_as_int(t + MAGICA) & 8191;
}

// ---------------- Kernel A: xq[m][n] = rint((W_ih·x + b) * WHS), int32. (R9 proven)
#define XP_GRID 256
#define XP_NT   ((B_ * T_ / 16) / XP_GRID)   // 16 m-tiles per block
__global__ __launch_bounds__(256, 1)
void xp_kernel(const float* __restrict__ x, const float* __restrict__ W_ih,
               const float* __restrict__ b_ih, const float* __restrict__ b_hh,
               int* __restrict__ xq) {
    const int tid  = threadIdx.x;
    const int wave = tid >> 6, lane = tid & 63;
    const int l15  = lane & 15, quad = lane >> 4;
    const int n0   = wave * 64;

    short8 wfrag[4][4];
#pragma unroll
    for (int mtt = 0; mtt < 4; ++mtt)
#pragma unroll
        for (int kq = 0; kq < 4; ++kq) {
            const float* p = W_ih + (long)(n0 + mtt * 16 + l15) * I_ + kq * 32 + quad * 8;
            wfrag[mtt][kq] = pack8(*(const float4*)p, *(const float4*)(p + 4));
        }
    floatx4 biasv[4];
#pragma unroll
    for (int mtt = 0; mtt < 4; ++mtt)
#pragma unroll
        for (int r = 0; r < 4; ++r) {
            int n = n0 + mtt * 16 + quad * 4 + r;
            biasv[mtt][r] = b_ih[n] + b_hh[n];
        }

    const long mbase = (long)blockIdx.x * XP_NT * 16;

    float4 qa[4][2], qb[4][2];
#define LDX(Q, IT)                                                              \
    {                                                                           \
        const int itc = ((IT) < XP_NT) ? (IT) : (XP_NT - 1);                    \
        const float* p = x + (mbase + (long)itc * 16 + l15) * I_ + quad * 8;    \
        _Pragma("unroll")                                                       \
        for (int kq = 0; kq < 4; ++kq) {                                        \
            Q[kq][0] = *(const float4*)(p + kq * 32);                           \
            Q[kq][1] = *(const float4*)(p + kq * 32 + 4);                       \
        }                                                                       \
    }
#define ITER(Q, IT, ILD)                                                        \
    {                                                                           \
        short8 xf[4];                                                           \
        _Pragma("unroll")                                                       \
        for (int kq = 0; kq < 4; ++kq) xf[kq] = pack8(Q[kq][0], Q[kq][1]);      \
        LDX(Q, ILD);                                                            \
        floatx4 acc[4];                                                         \
        _Pragma("unroll")                                                       \
        for (int mtt = 0; mtt < 4; ++mtt) acc[mtt] = biasv[mtt];                \
        _Pragma("unroll")                                                       \
        for (int kq = 0; kq < 4; ++kq)                                          \
            _Pragma("unroll")                                                   \
            for (int mtt = 0; mtt < 4; ++mtt)                                   \
                acc[mtt] = __builtin_amdgcn_mfma_f32_16x16x32_bf16(             \
                    wfrag[mtt][kq], xf[kq], acc[mtt], 0, 0, 0);                 \
        int* o = xq + (mbase + (long)(IT) * 16 + l15) * H_ + n0 + quad * 4;     \
        _Pragma("unroll")                                                       \
        for (int mtt = 0; mtt < 4; ++mtt) {                                     \
            int4 st;                                                            \
            st.x = (int)rintf(acc[mtt][0] * WHS);                               \
            st.y = (int)rintf(acc[mtt][1] * WHS);                               \
            st.z = (int)rintf(acc[mtt][2] * WHS);                               \
            st.w = (int)rintf(acc[mtt][3] * WHS);                               \
            *(int4*)(o + mtt * 16) = st;                                        \
        }                                                                       \
    }

    LDX(qa, 0);
    LDX(qb, 1);
#pragma unroll 1
    for (int it = 0; it < XP_NT; it += 2) {
        ITER(qa, it, it + 2);
        ITER(qb, it + 1, it + 3);
    }
#undef ITER
#undef LDX
}

// ---------------- Kernel B: int8 MFMA recurrence + LUT epilogue.
// 8 blocks x 16 batches, 8 waves. Per step: 4 h ds_read_b128 | seed acc = xq |
// 8 MFMA i8 K=64 | LUT index (5 VALU/elem) -> 8 ds_read_i8 | perm-pack |
// ds_write_b32 | BAR.
__global__ __launch_bounds__(512, 2)
void rnn_kernel(const int* __restrict__ xq, const float* __restrict__ W_hh,
                const float* __restrict__ W_fc, const float* __restrict__ b_fc,
                float* __restrict__ out) {
    __shared__ __align__(16) signed char hbuf[2][16][256];
    __shared__ __align__(16) signed char lut[8192];   // q = rint(127*tanh(z)), v=2log2e*z
    const int tid  = threadIdx.x;
    const int wave = tid >> 6, lane = tid & 63;
    const int l15  = lane & 15, quad = lane >> 4;
    const int b0   = blockIdx.x * 16;
    const int n0   = wave * 32;
    const int swz  = l15 & 7;

    // W_hh int8 A-fragments: [mt][kq], row n0+mt*16+l15, K-bytes kq*64+quad*16
    int4v wfrag[2][4];
#pragma unroll
    for (int mt = 0; mt < 2; ++mt)
#pragma unroll
        for (int kq = 0; kq < 4; ++kq) {
            const float* p = W_hh + (long)(n0 + mt * 16 + l15) * H_ + kq * 64 + quad * 16;
            int4v f;
#pragma unroll
            for (int j = 0; j < 4; ++j) {
                float4 w = *(const float4*)(p + j * 4);
                f[j] = q4(w.x, w.y, w.z, w.w, WSC);
            }
            wfrag[mt][kq] = f;
        }

    // build LUT: entry i -> rint(127*tanh(z)), v_i = (i-4096)/256 = 2log2e*z
    for (int i = tid; i < 8192; i += 512) {
        float v = (float)(i - 4096) * (1.0f / 256.0f);
        float e = __builtin_amdgcn_exp2f(v);          // e^{2z}
        float th = 1.0f - 2.0f / (e + 1.0f);
        lut[i] = (signed char)(int)rintf(127.0f * th);
    }
    // zero hbuf[0] (h_0 = 0)
    {
        int* hz = (int*)&hbuf[0][0][0];
        for (int i = tid; i < 2 * 16 * 256 / 4; i += 512) hz[i] = 0;
    }

    // LDS offsets (bytes); 16 16B-blocks per 256B row
    int roff[4];
#pragma unroll
    for (int kq = 0; kq < 4; ++kq)
        roff[kq] = l15 * 256 + (((kq * 4 + quad) ^ swz) << 4);
    int woff[2];
#pragma unroll
    for (int mt = 0; mt < 2; ++mt) {
        int c = wave * 2 + mt;
        woff[mt] = l15 * 256 + ((c ^ swz) << 4) + quad * 4;
    }

    // xq prefetch: lane holds 2 int4 (mt=0 at +0, mt=1 at +16)
    const int* xql = xq + (long)(b0 + l15) * T_ * H_ + n0 + quad * 4;
    int4v xvA0 = *(const int4v*)(xql);
    int4v xvA1 = *(const int4v*)(xql + 16);
    int4v xvB0 = *(const int4v*)(xql + H_);
    int4v xvB1 = *(const int4v*)(xql + H_ + 16);

    __syncthreads();   // LUT + hbuf zero visible

    const signed char* hb0r = &hbuf[0][0][0]; signed char* hb0w = &hbuf[0][0][0];
    const signed char* hb1r = &hbuf[1][0][0]; signed char* hb1w = &hbuf[1][0][0];

#define BAR() asm volatile("s_waitcnt lgkmcnt(0)\n\ts_barrier" ::: "memory")

#define STEP(HR, HW, XV0, XV1, TLD)                                             \
    {                                                                           \
        /* 1. h-fragment reads (4 b128) — critical-path latency */              \
        int4v hfrag[4];                                                         \
        _Pragma("unroll")                                                       \
        for (int kq = 0; kq < 4; ++kq)                                          \
            hfrag[kq] = *(const int4v*)((HR) + roff[kq]);                       \
        /* 2. seed accumulators from xq; reload XV for t+2 */                   \
        int4v aC[2];                                                            \
        aC[0] = XV0; aC[1] = XV1;                                               \
        XV0 = *(const int4v*)(xql + (long)(TLD) * H_);                          \
        XV1 = *(const int4v*)(xql + (long)(TLD) * H_ + 16);                     \
        /* 3. 8 MFMAs: depth-4 chain per mt (2 independent chains) */           \
        _Pragma("unroll")                                                       \
        for (int kq = 0; kq < 4; ++kq)                                          \
            _Pragma("unroll")                                                   \
            for (int mt = 0; mt < 2; ++mt)                                      \
                aC[mt] = __builtin_amdgcn_mfma_i32_16x16x64_i8(                 \
                    wfrag[mt][kq], hfrag[kq], aC[mt], 0, 0, 0);                 \
        /* 4. epilogue: LUT gather (both mt's issued before packing) */         \
        int g[2][4];                                                            \
        _Pragma("unroll")                                                       \
        for (int mt = 0; mt < 2; ++mt) {                                        \
            g[mt][0] = lut[lut_idx(aC[mt][0])];                                 \
            g[mt][1] = lut[lut_idx(aC[mt][1])];                                 \
            g[mt][2] = lut[lut_idx(aC[mt][2])];                                 \
            g[mt][3] = lut[lut_idx(aC[mt][3])];                                 \
        }                                                                       \
        _Pragma("unroll")                                                       \
        for (int mt = 0; mt < 2; ++mt) {                                        \
            unsigned t01 = __builtin_amdgcn_perm(                               \
                (unsigned)g[mt][1], (unsigned)g[mt][0], 0x00000400u);           \
            unsigned t23 = __builtin_amdgcn_perm(                               \
                (unsigned)g[mt][3], (unsigned)g[mt][2], 0x00000400u);           \
            unsigned pk  = __builtin_amdgcn_perm(t23, t01, 0x05040100u);        \
            *(int*)((HW) + woff[mt]) = (int)pk;                                 \
        }                                                                       \
        BAR();                                                                  \
    }

#pragma unroll 1
    for (int t = 0; t < T_; t += 2) {
        const int tl0 = (t + 2 < T_) ? t + 2 : T_ - 1;
        const int tl1 = (t + 3 < T_) ? t + 3 : T_ - 1;
        STEP(hb0r, hb1w, xvA0, xvA1, tl0);   // even t: read buf0, write buf1
        STEP(hb1r, hb0w, xvB0, xvB1, tl1);   // odd t:  read buf1, write buf0
    }
#undef STEP
#undef BAR

    // head: out[b] = sigmoid(b_fc + (1/HSC)*sum_n hq[b][n]*W_fc[n]); h_T in hbuf[0]
    if (tid < 256) {
        const int bl = tid >> 4, seg = tid & 15;
        const int bswz = bl & 7;
        const signed char* hr = &hbuf[0][0][0] + bl * 256 + ((seg ^ bswz) << 4);
        float p = 0.0f;
#pragma unroll
        for (int i = 0; i < 16; ++i)
            p += (float)hr[i] * W_fc[seg * 16 + i];
#pragma unroll
        for (int off = 1; off < 16; off <<= 1) p += __shfl_xor(p, off);
        if (seg == 0)
            out[b0 + bl] = 1.0f / (1.0f + __expf(-(p * (1.0f / HSC) + b_fc[0])));
    }
}

extern "C" void kernel_launch(void* const* d_in, const int* in_sizes, int n_in,
                              void* d_out, int out_size, void* d_ws, size_t ws_size,
                              hipStream_t stream) {
    const float* x    = (const float*)d_in[0];
    const float* W_ih = (const float*)d_in[1];
    const float* W_hh = (const float*)d_in[2];
    const float* b_ih = (const float*)d_in[3];
    const float* b_hh = (const float*)d_in[4];
    const float* W_fc = (const float*)d_in[5];
    const float* b_fc = (const float*)d_in[6];
    float* out = (float*)d_out;

    int* xq = (int*)d_ws;   // B*T*H int32 = 67.1 MB

    xp_kernel<<<XP_GRID, 256, 0, stream>>>(x, W_ih, b_ih, b_hh, xq);
    rnn_kernel<<<B_ / 16, 512, 0, stream>>>(xq, W_hh, W_fc, b_fc, out);
}

// Round 13
// 341.231 us; speedup vs baseline: 1.2452x; 1.0312x over previous
//
#include <hip/hip_runtime.h>
#include <hip/hip_bf16.h>

// B=128, T=512, I=128, H=256, O=1 (fp32 in/out)
// R13: CU-doubling batch split. R10 showed no pipe saturated (DS ~65%, VALU
// ~37%, MFMA ~20%) -> step is phase-serialization-bound on only 8 CUs. The
// per-wave DS-read floor (4 ds_read_b128 = full K=256 B-frag) is INDEPENDENT
// of batch count, so: 16 blocks x 8 batches = 2x CUs at ~same per-CU step.
// Lanes l15>=8 compute garbage cols (zeroed hbuf rows, clamped xq ptr,
// clamped LUT idx) and are masked at the h-write only.
//   + i8 MFMA chain split depth-4 -> 2+2 with int-add merge (R6 pattern).
// Carries: LUT tanh epilogue (R10), xq int32 acc-seed (R9), int8 h/W (R8),
// XOR-swizzled LDS + raw BAR (R2/R6).

#define B_ 128
#define T_ 512
#define I_ 128
#define H_ 256
#define BB 8                         // batches per block (R13: was 16)
#define SCALE 2.8853900817779268f    // 2*log2(e)
#define WSC 2032.0f                  // W_hh int8 scale (127*16; |W|<=1/16 exact)
#define HSC 127.0f                   // h int8 scale
#define WHS (WSC * HSC)              // 258064: xp pre-quant scale
#define K1F (SCALE * 256.0f / WHS)   // i32 acc -> LUT index units (v * 256)
#define MAGICA 12582912.0f           // 2^23 + 2^22 (mantissa-int trick)

typedef __attribute__((ext_vector_type(8))) short short8;
typedef __attribute__((ext_vector_type(4))) float floatx4;
typedef __attribute__((ext_vector_type(4))) int int4v;

__device__ __forceinline__ short8 pack8(float4 lo, float4 hi) {
    __hip_bfloat162 p0 = __float22bfloat162_rn(float2{lo.x, lo.y});
    __hip_bfloat162 p1 = __float22bfloat162_rn(float2{lo.z, lo.w});
    __hip_bfloat162 p2 = __float22bfloat162_rn(float2{hi.x, hi.y});
    __hip_bfloat162 p3 = __float22bfloat162_rn(float2{hi.z, hi.w});
    int4 i;
    i.x = *(int*)&p0; i.y = *(int*)&p1; i.z = *(int*)&p2; i.w = *(int*)&p3;
    return *(short8*)&i;
}
// quantize 4 floats (|v*s| <= 127) -> packed int8 dword, RNE (W_hh setup only)
__device__ __forceinline__ int q4(float a, float b, float c, float d, float s) {
    int qa = (int)rintf(a * s) & 255;
    int qb = (int)rintf(b * s) & 255;
    int qc = (int)rintf(c * s) & 255;
    int qd = (int)rintf(d * s) & 255;
    return qa | (qb << 8) | (qc << 16) | (qd << 24);
}
// i32 acc -> LUT index: t = clamp(acc*K1F + 4096, 0, 8191); idx = rint(t)
__device__ __forceinline__ int lut_idx(int acci) {
    float t = __builtin_fmaf((float)acci, K1F, 4096.0f);
    t = fminf(fmaxf(t, 0.0f), 8191.0f);
    return __float_as_int(t + MAGICA) & 8191;
}

// ---------------- Kernel A: xq[m][n] = rint((W_ih·x + b) * WHS), int32. (R9 proven)
#define XP_GRID 256
#define XP_NT   ((B_ * T_ / 16) / XP_GRID)   // 16 m-tiles per block
__global__ __launch_bounds__(256, 1)
void xp_kernel(const float* __restrict__ x, const float* __restrict__ W_ih,
               const float* __restrict__ b_ih, const float* __restrict__ b_hh,
               int* __restrict__ xq) {
    const int tid  = threadIdx.x;
    const int wave = tid >> 6, lane = tid & 63;
    const int l15  = lane & 15, quad = lane >> 4;
    const int n0   = wave * 64;

    short8 wfrag[4][4];
#pragma unroll
    for (int mtt = 0; mtt < 4; ++mtt)
#pragma unroll
        for (int kq = 0; kq < 4; ++kq) {
            const float* p = W_ih + (long)(n0 + mtt * 16 + l15) * I_ + kq * 32 + quad * 8;
            wfrag[mtt][kq] = pack8(*(const float4*)p, *(const float4*)(p + 4));
        }
    floatx4 biasv[4];
#pragma unroll
    for (int mtt = 0; mtt < 4; ++mtt)
#pragma unroll
        for (int r = 0; r < 4; ++r) {
            int n = n0 + mtt * 16 + quad * 4 + r;
            biasv[mtt][r] = b_ih[n] + b_hh[n];
        }

    const long mbase = (long)blockIdx.x * XP_NT * 16;

    float4 qa[4][2], qb[4][2];
#define LDX(Q, IT)                                                              \
    {                                                                           \
        const int itc = ((IT) < XP_NT) ? (IT) : (XP_NT - 1);                    \
        const float* p = x + (mbase + (long)itc * 16 + l15) * I_ + quad * 8;    \
        _Pragma("unroll")                                                       \
        for (int kq = 0; kq < 4; ++kq) {                                        \
            Q[kq][0] = *(const float4*)(p + kq * 32);                           \
            Q[kq][1] = *(const float4*)(p + kq * 32 + 4);                       \
        }                                                                       \
    }
#define ITER(Q, IT, ILD)                                                        \
    {                                                                           \
        short8 xf[4];                                                           \
        _Pragma("unroll")                                                       \
        for (int kq = 0; kq < 4; ++kq) xf[kq] = pack8(Q[kq][0], Q[kq][1]);      \
        LDX(Q, ILD);                                                            \
        floatx4 acc[4];                                                         \
        _Pragma("unroll")                                                       \
        for (int mtt = 0; mtt < 4; ++mtt) acc[mtt] = biasv[mtt];                \
        _Pragma("unroll")                                                       \
        for (int kq = 0; kq < 4; ++kq)                                          \
            _Pragma("unroll")                                                   \
            for (int mtt = 0; mtt < 4; ++mtt)                                   \
                acc[mtt] = __builtin_amdgcn_mfma_f32_16x16x32_bf16(             \
                    wfrag[mtt][kq], xf[kq], acc[mtt], 0, 0, 0);                 \
        int* o = xq + (mbase + (long)(IT) * 16 + l15) * H_ + n0 + quad * 4;     \
        _Pragma("unroll")                                                       \
        for (int mtt = 0; mtt < 4; ++mtt) {                                     \
            int4 st;                                                            \
            st.x = (int)rintf(acc[mtt][0] * WHS);                               \
            st.y = (int)rintf(acc[mtt][1] * WHS);                               \
            st.z = (int)rintf(acc[mtt][2] * WHS);                               \
            st.w = (int)rintf(acc[mtt][3] * WHS);                               \
            *(int4*)(o + mtt * 16) = st;                                        \
        }                                                                       \
    }

    LDX(qa, 0);
    LDX(qb, 1);
#pragma unroll 1
    for (int it = 0; it < XP_NT; it += 2) {
        ITER(qa, it, it + 2);
        ITER(qb, it + 1, it + 3);
    }
#undef ITER
#undef LDX
}

// ---------------- Kernel B: int8 MFMA recurrence + LUT epilogue, BB=8 batches.
// 16 blocks x 8 waves. Per step: 4 h ds_read_b128 | seed acc = xq | 8 MFMA i8
// K=64 (2+2 split chains + int merge) | LUT gather | perm-pack | masked
// ds_write_b32 (l15<BB) | BAR.
__global__ __launch_bounds__(512, 2)
void rnn_kernel(const int* __restrict__ xq, const float* __restrict__ W_hh,
                const float* __restrict__ W_fc, const float* __restrict__ b_fc,
                float* __restrict__ out) {
    __shared__ __align__(16) signed char hbuf[2][16][256];
    __shared__ __align__(16) signed char lut[8192];   // q = rint(127*tanh(z)), v=2log2e*z
    const int tid  = threadIdx.x;
    const int wave = tid >> 6, lane = tid & 63;
    const int l15  = lane & 15, quad = lane >> 4;
    const int b0   = blockIdx.x * BB;
    const int n0   = wave * 32;
    const int swz  = l15 & 7;

    // W_hh int8 A-fragments: [mt][kq], row n0+mt*16+l15, K-bytes kq*64+quad*16
    int4v wfrag[2][4];
#pragma unroll
    for (int mt = 0; mt < 2; ++mt)
#pragma unroll
        for (int kq = 0; kq < 4; ++kq) {
            const float* p = W_hh + (long)(n0 + mt * 16 + l15) * H_ + kq * 64 + quad * 16;
            int4v f;
#pragma unroll
            for (int j = 0; j < 4; ++j) {
                float4 w = *(const float4*)(p + j * 4);
                f[j] = q4(w.x, w.y, w.z, w.w, WSC);
            }
            wfrag[mt][kq] = f;
        }

    // build LUT: entry i -> rint(127*tanh(z)), v_i = (i-4096)/256 = 2log2e*z
    for (int i = tid; i < 8192; i += 512) {
        float v = (float)(i - 4096) * (1.0f / 256.0f);
        float e = __builtin_amdgcn_exp2f(v);          // e^{2z}
        float th = 1.0f - 2.0f / (e + 1.0f);
        lut[i] = (signed char)(int)rintf(127.0f * th);
    }
    // zero both h buffers fully (rows BB..15 stay zero forever — read-safe)
    {
        int* hz = (int*)&hbuf[0][0][0];
        for (int i = tid; i < 2 * 16 * 256 / 4; i += 512) hz[i] = 0;
    }

    // LDS offsets (bytes); 16 16B-blocks per 256B row
    int roff[4];
#pragma unroll
    for (int kq = 0; kq < 4; ++kq)
        roff[kq] = l15 * 256 + (((kq * 4 + quad) ^ swz) << 4);
    int woff[2];
#pragma unroll
    for (int mt = 0; mt < 2; ++mt) {
        int c = wave * 2 + mt;
        woff[mt] = l15 * 256 + ((c ^ swz) << 4) + quad * 4;
    }

    // xq prefetch: lane holds 2 int4; batch index clamped in-bounds for l15>=BB
    const int bcl = (l15 < BB) ? l15 : (BB - 1);
    const int* xql = xq + (long)(b0 + bcl) * T_ * H_ + n0 + quad * 4;
    int4v xvA0 = *(const int4v*)(xql);
    int4v xvA1 = *(const int4v*)(xql + 16);
    int4v xvB0 = *(const int4v*)(xql + H_);
    int4v xvB1 = *(const int4v*)(xql + H_ + 16);

    __syncthreads();   // LUT + hbuf zero visible

    const signed char* hb0r = &hbuf[0][0][0]; signed char* hb0w = &hbuf[0][0][0];
    const signed char* hb1r = &hbuf[1][0][0]; signed char* hb1w = &hbuf[1][0][0];

#define BAR() asm volatile("s_waitcnt lgkmcnt(0)\n\ts_barrier" ::: "memory")

#define STEP(HR, HW, XV0, XV1, TLD)                                             \
    {                                                                           \
        /* 1. h-fragment reads (4 b128) — critical-path latency */              \
        int4v hfrag[4];                                                         \
        _Pragma("unroll")                                                       \
        for (int kq = 0; kq < 4; ++kq)                                          \
            hfrag[kq] = *(const int4v*)((HR) + roff[kq]);                       \
        /* 2. seed aC from xq (aZ zero); reload XV for t+2 */                   \
        int4v aC[2], aZ[2];                                                     \
        aC[0] = XV0; aC[1] = XV1;                                               \
        aZ[0] = (int4v){0, 0, 0, 0};                                            \
        aZ[1] = (int4v){0, 0, 0, 0};                                            \
        XV0 = *(const int4v*)(xql + (long)(TLD) * H_);                          \
        XV1 = *(const int4v*)(xql + (long)(TLD) * H_ + 16);                     \
        /* 3. 8 MFMAs: 2+2 split chains per mt (4 independent depth-2) */       \
        _Pragma("unroll")                                                       \
        for (int kq = 0; kq < 2; ++kq)                                          \
            _Pragma("unroll")                                                   \
            for (int mt = 0; mt < 2; ++mt) {                                    \
                aC[mt] = __builtin_amdgcn_mfma_i32_16x16x64_i8(                 \
                    wfrag[mt][kq], hfrag[kq], aC[mt], 0, 0, 0);                 \
                aZ[mt] = __builtin_amdgcn_mfma_i32_16x16x64_i8(                 \
                    wfrag[mt][kq + 2], hfrag[kq + 2], aZ[mt], 0, 0, 0);         \
            }                                                                   \
        /* 4. epilogue: merge, LUT gather (idx clamped — garbage lanes safe) */ \
        int g[2][4];                                                            \
        _Pragma("unroll")                                                       \
        for (int mt = 0; mt < 2; ++mt) {                                        \
            g[mt][0] = lut[lut_idx(aC[mt][0] + aZ[mt][0])];                     \
            g[mt][1] = lut[lut_idx(aC[mt][1] + aZ[mt][1])];                     \
            g[mt][2] = lut[lut_idx(aC[mt][2] + aZ[mt][2])];                     \
            g[mt][3] = lut[lut_idx(aC[mt][3] + aZ[mt][3])];                     \
        }                                                                       \
        if (l15 < BB) {                                                         \
            _Pragma("unroll")                                                   \
            for (int mt = 0; mt < 2; ++mt) {                                    \
                unsigned t01 = __builtin_amdgcn_perm(                           \
                    (unsigned)g[mt][1], (unsigned)g[mt][0], 0x00000400u);       \
                unsigned t23 = __builtin_amdgcn_perm(                           \
                    (unsigned)g[mt][3], (unsigned)g[mt][2], 0x00000400u);       \
                unsigned pk  = __builtin_amdgcn_perm(t23, t01, 0x05040100u);    \
                *(int*)((HW) + woff[mt]) = (int)pk;                             \
            }                                                                   \
        }                                                                       \
        BAR();                                                                  \
    }

#pragma unroll 1
    for (int t = 0; t < T_; t += 2) {
        const int tl0 = (t + 2 < T_) ? t + 2 : T_ - 1;
        const int tl1 = (t + 3 < T_) ? t + 3 : T_ - 1;
        STEP(hb0r, hb1w, xvA0, xvA1, tl0);   // even t: read buf0, write buf1
        STEP(hb1r, hb0w, xvB0, xvB1, tl1);   // odd t:  read buf1, write buf0
    }
#undef STEP
#undef BAR

    // head: out[b] = sigmoid(b_fc + (1/HSC)*sum_n hq[b][n]*W_fc[n]); h_T in hbuf[0]
    if (tid < BB * 16) {
        const int bl = tid >> 4, seg = tid & 15;
        const int bswz = bl & 7;
        const signed char* hr = &hbuf[0][0][0] + bl * 256 + ((seg ^ bswz) << 4);
        float p = 0.0f;
#pragma unroll
        for (int i = 0; i < 16; ++i)
            p += (float)hr[i] * W_fc[seg * 16 + i];
#pragma unroll
        for (int off = 1; off < 16; off <<= 1) p += __shfl_xor(p, off);
        if (seg == 0)
            out[b0 + bl] = 1.0f / (1.0f + __expf(-(p * (1.0f / HSC) + b_fc[0])));
    }
}

extern "C" void kernel_launch(void* const* d_in, const int* in_sizes, int n_in,
                              void* d_out, int out_size, void* d_ws, size_t ws_size,
                              hipStream_t stream) {
    const float* x    = (const float*)d_in[0];
    const float* W_ih = (const float*)d_in[1];
    const float* W_hh = (const float*)d_in[2];
    const float* b_ih = (const float*)d_in[3];
    const float* b_hh = (const float*)d_in[4];
    const float* W_fc = (const float*)d_in[5];
    const float* b_fc = (const float*)d_in[6];
    float* out = (float*)d_out;

    int* xq = (int*)d_ws;   // B*T*H int32 = 67.1 MB

    xp_kernel<<<XP_GRID, 256, 0, stream>>>(x, W_ih, b_ih, b_hh, xq);
    rnn_kernel<<<B_ / BB, 512, 0, stream>>>(xq, W_hh, W_fc, b_fc, out);
}

// Round 14
// 333.233 us; speedup vs baseline: 1.2751x; 1.0240x over previous
//
#include <hip/hip_runtime.h>
#include <hip/hip_bf16.h>

// B=128, T=512, I=128, H=256, O=1 (fp32 in/out)
// R14: BB=8 split + gather-free epilogue, fully masked.
// R13 lesson: DS pipe was saturated and LUT gathers were ~half of it; masking
// only writes left per-CU DS work unchanged -> no gain from 2x CUs. R14:
//   * revert LUT -> R9's exp2+rcp+fused-magic-quantize epilogue (absmax-proven)
//   * BB=8, 16 blocks; ENTIRE epilogue (merge, tanh, quantize, pack, write)
//     under if(l15<BB) -> half the VALU/trans, zero DS gathers
//   * keeps: xq int32 acc-seed (R9), int8 h/W + i8 K=64 MFMA (R8), 2+2 chain
//     split (R13), XOR-swizzled LDS + raw lgkmcnt-only BAR (R2/R6).
// Per-CU-step budget (measured rates): DS ~600cy, VALU+trans ~450cy/SIMD,
// MFMA ~130cy -> step ~750-850cy (was 1136).

#define B_ 128
#define T_ 512
#define I_ 128
#define H_ 256
#define BB 8                         // batches per block
#define SCALE 2.8853900817779268f    // 2*log2(e)
#define WSC 2032.0f                  // W_hh int8 scale (127*16; |W|<=1/16 exact)
#define HSC 127.0f                   // h int8 scale
#define WHS (WSC * HSC)              // 258064: xp pre-quant scale
#define SCOMB (SCALE / WHS)          // i32 acc -> prescaled preact
#define MAGICQ 12583039.0f           // 2^23 + 2^22 + 127 (RNE int8 in low byte)

typedef __attribute__((ext_vector_type(8))) short short8;
typedef __attribute__((ext_vector_type(4))) float floatx4;
typedef __attribute__((ext_vector_type(4))) int int4v;

__device__ __forceinline__ short8 pack8(float4 lo, float4 hi) {
    __hip_bfloat162 p0 = __float22bfloat162_rn(float2{lo.x, lo.y});
    __hip_bfloat162 p1 = __float22bfloat162_rn(float2{lo.z, lo.w});
    __hip_bfloat162 p2 = __float22bfloat162_rn(float2{hi.x, hi.y});
    __hip_bfloat162 p3 = __float22bfloat162_rn(float2{hi.z, hi.w});
    int4 i;
    i.x = *(int*)&p0; i.y = *(int*)&p1; i.z = *(int*)&p2; i.w = *(int*)&p3;
    return *(short8*)&i;
}
// quantize 4 floats (|v*s| <= 127) -> packed int8 dword, RNE (W_hh setup only)
__device__ __forceinline__ int q4(float a, float b, float c, float d, float s) {
    int qa = (int)rintf(a * s) & 255;
    int qb = (int)rintf(b * s) & 255;
    int qc = (int)rintf(c * s) & 255;
    int qd = (int)rintf(d * s) & 255;
    return qa | (qb << 8) | (qc << 16) | (qd << 24);
}
// tanh+quantize fused (R9-proven): v = acc*SCOMB (prescaled), q = 127-254*rcp,
// fma(-254, rcp, MAGICQ) puts RNE two's-complement int8 in the low mantissa byte.
__device__ __forceinline__ float tq(int acci) {
    float v = (float)acci * SCOMB;
    float e = __builtin_amdgcn_exp2f(v);          // e^{2z}
    float rc = __builtin_amdgcn_rcpf(e + 1.0f);
    return __builtin_fmaf(-254.0f, rc, MAGICQ);
}

// ---------------- Kernel A: xq[m][n] = rint((W_ih·x + b) * WHS), int32. (R9 proven)
#define XP_GRID 256
#define XP_NT   ((B_ * T_ / 16) / XP_GRID)   // 16 m-tiles per block
__global__ __launch_bounds__(256, 1)
void xp_kernel(const float* __restrict__ x, const float* __restrict__ W_ih,
               const float* __restrict__ b_ih, const float* __restrict__ b_hh,
               int* __restrict__ xq) {
    const int tid  = threadIdx.x;
    const int wave = tid >> 6, lane = tid & 63;
    const int l15  = lane & 15, quad = lane >> 4;
    const int n0   = wave * 64;

    short8 wfrag[4][4];
#pragma unroll
    for (int mtt = 0; mtt < 4; ++mtt)
#pragma unroll
        for (int kq = 0; kq < 4; ++kq) {
            const float* p = W_ih + (long)(n0 + mtt * 16 + l15) * I_ + kq * 32 + quad * 8;
            wfrag[mtt][kq] = pack8(*(const float4*)p, *(const float4*)(p + 4));
        }
    floatx4 biasv[4];
#pragma unroll
    for (int mtt = 0; mtt < 4; ++mtt)
#pragma unroll
        for (int r = 0; r < 4; ++r) {
            int n = n0 + mtt * 16 + quad * 4 + r;
            biasv[mtt][r] = b_ih[n] + b_hh[n];
        }

    const long mbase = (long)blockIdx.x * XP_NT * 16;

    float4 qa[4][2], qb[4][2];
#define LDX(Q, IT)                                                              \
    {                                                                           \
        const int itc = ((IT) < XP_NT) ? (IT) : (XP_NT - 1);                    \
        const float* p = x + (mbase + (long)itc * 16 + l15) * I_ + quad * 8;    \
        _Pragma("unroll")                                                       \
        for (int kq = 0; kq < 4; ++kq) {                                        \
            Q[kq][0] = *(const float4*)(p + kq * 32);                           \
            Q[kq][1] = *(const float4*)(p + kq * 32 + 4);                       \
        }                                                                       \
    }
#define ITER(Q, IT, ILD)                                                        \
    {                                                                           \
        short8 xf[4];                                                           \
        _Pragma("unroll")                                                       \
        for (int kq = 0; kq < 4; ++kq) xf[kq] = pack8(Q[kq][0], Q[kq][1]);      \
        LDX(Q, ILD);                                                            \
        floatx4 acc[4];                                                         \
        _Pragma("unroll")                                                       \
        for (int mtt = 0; mtt < 4; ++mtt) acc[mtt] = biasv[mtt];                \
        _Pragma("unroll")                                                       \
        for (int kq = 0; kq < 4; ++kq)                                          \
            _Pragma("unroll")                                                   \
            for (int mtt = 0; mtt < 4; ++mtt)                                   \
                acc[mtt] = __builtin_amdgcn_mfma_f32_16x16x32_bf16(             \
                    wfrag[mtt][kq], xf[kq], acc[mtt], 0, 0, 0);                 \
        int* o = xq + (mbase + (long)(IT) * 16 + l15) * H_ + n0 + quad * 4;     \
        _Pragma("unroll")                                                       \
        for (int mtt = 0; mtt < 4; ++mtt) {                                     \
            int4 st;                                                            \
            st.x = (int)rintf(acc[mtt][0] * WHS);                               \
            st.y = (int)rintf(acc[mtt][1] * WHS);                               \
            st.z = (int)rintf(acc[mtt][2] * WHS);                               \
            st.w = (int)rintf(acc[mtt][3] * WHS);                               \
            *(int4*)(o + mtt * 16) = st;                                        \
        }                                                                       \
    }

    LDX(qa, 0);
    LDX(qb, 1);
#pragma unroll 1
    for (int it = 0; it < XP_NT; it += 2) {
        ITER(qa, it, it + 2);
        ITER(qb, it + 1, it + 3);
    }
#undef ITER
#undef LDX
}

// ---------------- Kernel B: int8 MFMA recurrence, BB=8 batches, 16 blocks x 8 waves.
// Per step: 4 h ds_read_b128 | seed aC = xq, aZ = 0 | 8 MFMA i8 K=64 (2+2
// split chains) | masked epilogue (merge, exp2-tanh+quantize, perm-pack,
// ds_write_b32, l15<BB only) | BAR.
__global__ __launch_bounds__(512, 2)
void rnn_kernel(const int* __restrict__ xq, const float* __restrict__ W_hh,
                const float* __restrict__ W_fc, const float* __restrict__ b_fc,
                float* __restrict__ out) {
    __shared__ __align__(16) signed char hbuf[2][16][256];
    const int tid  = threadIdx.x;
    const int wave = tid >> 6, lane = tid & 63;
    const int l15  = lane & 15, quad = lane >> 4;
    const int b0   = blockIdx.x * BB;
    const int n0   = wave * 32;
    const int swz  = l15 & 7;

    // W_hh int8 A-fragments: [mt][kq], row n0+mt*16+l15, K-bytes kq*64+quad*16
    int4v wfrag[2][4];
#pragma unroll
    for (int mt = 0; mt < 2; ++mt)
#pragma unroll
        for (int kq = 0; kq < 4; ++kq) {
            const float* p = W_hh + (long)(n0 + mt * 16 + l15) * H_ + kq * 64 + quad * 16;
            int4v f;
#pragma unroll
            for (int j = 0; j < 4; ++j) {
                float4 w = *(const float4*)(p + j * 4);
                f[j] = q4(w.x, w.y, w.z, w.w, WSC);
            }
            wfrag[mt][kq] = f;
        }

    // zero both h buffers fully (rows BB..15 stay zero forever — read-safe)
    {
        int* hz = (int*)&hbuf[0][0][0];
        for (int i = tid; i < 2 * 16 * 256 / 4; i += 512) hz[i] = 0;
    }

    // LDS offsets (bytes); 16 16B-blocks per 256B row
    int roff[4];
#pragma unroll
    for (int kq = 0; kq < 4; ++kq)
        roff[kq] = l15 * 256 + (((kq * 4 + quad) ^ swz) << 4);
    int woff[2];
#pragma unroll
    for (int mt = 0; mt < 2; ++mt) {
        int c = wave * 2 + mt;
        woff[mt] = l15 * 256 + ((c ^ swz) << 4) + quad * 4;
    }

    // xq prefetch: lane holds 2 int4; batch index clamped in-bounds for l15>=BB
    const int bcl = (l15 < BB) ? l15 : (BB - 1);
    const int* xql = xq + (long)(b0 + bcl) * T_ * H_ + n0 + quad * 4;
    int4v xvA0 = *(const int4v*)(xql);
    int4v xvA1 = *(const int4v*)(xql + 16);
    int4v xvB0 = *(const int4v*)(xql + H_);
    int4v xvB1 = *(const int4v*)(xql + H_ + 16);

    __syncthreads();   // hbuf zero visible

    const signed char* hb0r = &hbuf[0][0][0]; signed char* hb0w = &hbuf[0][0][0];
    const signed char* hb1r = &hbuf[1][0][0]; signed char* hb1w = &hbuf[1][0][0];

#define BAR() asm volatile("s_waitcnt lgkmcnt(0)\n\ts_barrier" ::: "memory")

#define STEP(HR, HW, XV0, XV1, TLD)                                             \
    {                                                                           \
        /* 1. h-fragment reads (4 b128) — critical-path latency */              \
        int4v hfrag[4];                                                         \
        _Pragma("unroll")                                                       \
        for (int kq = 0; kq < 4; ++kq)                                          \
            hfrag[kq] = *(const int4v*)((HR) + roff[kq]);                       \
        /* 2. seed aC from xq (aZ zero); reload XV for t+2 */                   \
        int4v aC[2], aZ[2];                                                     \
        aC[0] = XV0; aC[1] = XV1;                                               \
        aZ[0] = (int4v){0, 0, 0, 0};                                            \
        aZ[1] = (int4v){0, 0, 0, 0};                                            \
        XV0 = *(const int4v*)(xql + (long)(TLD) * H_);                          \
        XV1 = *(const int4v*)(xql + (long)(TLD) * H_ + 16);                     \
        /* 3. 8 MFMAs: 2+2 split chains per mt (4 independent depth-2) */       \
        _Pragma("unroll")                                                       \
        for (int kq = 0; kq < 2; ++kq)                                          \
            _Pragma("unroll")                                                   \
            for (int mt = 0; mt < 2; ++mt) {                                    \
                aC[mt] = __builtin_amdgcn_mfma_i32_16x16x64_i8(                 \
                    wfrag[mt][kq], hfrag[kq], aC[mt], 0, 0, 0);                 \
                aZ[mt] = __builtin_amdgcn_mfma_i32_16x16x64_i8(                 \
                    wfrag[mt][kq + 2], hfrag[kq + 2], aZ[mt], 0, 0, 0);         \
            }                                                                   \
        /* 4. epilogue fully masked: only active batch lanes do any work */     \
        if (l15 < BB) {                                                         \
            _Pragma("unroll")                                                   \
            for (int mt = 0; mt < 2; ++mt) {                                    \
                float f0 = tq(aC[mt][0] + aZ[mt][0]);                           \
                float f1 = tq(aC[mt][1] + aZ[mt][1]);                           \
                float f2 = tq(aC[mt][2] + aZ[mt][2]);                           \
                float f3 = tq(aC[mt][3] + aZ[mt][3]);                           \
                unsigned t01 = __builtin_amdgcn_perm(                           \
                    *(unsigned*)&f1, *(unsigned*)&f0, 0x00000400u);             \
                unsigned t23 = __builtin_amdgcn_perm(                           \
                    *(unsigned*)&f3, *(unsigned*)&f2, 0x00000400u);             \
                unsigned pk  = __builtin_amdgcn_perm(t23, t01, 0x05040100u);    \
                *(int*)((HW) + woff[mt]) = (int)pk;                             \
            }                                                                   \
        }                                                                       \
        BAR();                                                                  \
    }

#pragma unroll 1
    for (int t = 0; t < T_; t += 2) {
        const int tl0 = (t + 2 < T_) ? t + 2 : T_ - 1;
        const int tl1 = (t + 3 < T_) ? t + 3 : T_ - 1;
        STEP(hb0r, hb1w, xvA0, xvA1, tl0);   // even t: read buf0, write buf1
        STEP(hb1r, hb0w, xvB0, xvB1, tl1);   // odd t:  read buf1, write buf0
    }
#undef STEP
#undef BAR

    // head: out[b] = sigmoid(b_fc + (1/HSC)*sum_n hq[b][n]*W_fc[n]); h_T in hbuf[0]
    if (tid < BB * 16) {
        const int bl = tid >> 4, seg = tid & 15;
        const int bswz = bl & 7;
        const signed char* hr = &hbuf[0][0][0] + bl * 256 + ((seg ^ bswz) << 4);
        float p = 0.0f;
#pragma unroll
        for (int i = 0; i < 16; ++i)
            p += (float)hr[i] * W_fc[seg * 16 + i];
#pragma unroll
        for (int off = 1; off < 16; off <<= 1) p += __shfl_xor(p, off);
        if (seg == 0)
            out[b0 + bl] = 1.0f / (1.0f + __expf(-(p * (1.0f / HSC) + b_fc[0])));
    }
}

extern "C" void kernel_launch(void* const* d_in, const int* in_sizes, int n_in,
                              void* d_out, int out_size, void* d_ws, size_t ws_size,
                              hipStream_t stream) {
    const float* x    = (const float*)d_in[0];
    const float* W_ih = (const float*)d_in[1];
    const float* W_hh = (const float*)d_in[2];
    const float* b_ih = (const float*)d_in[3];
    const float* b_hh = (const float*)d_in[4];
    const float* W_fc = (const float*)d_in[5];
    const float* b_fc = (const float*)d_in[6];
    float* out = (float*)d_out;

    int* xq = (int*)d_ws;   // B*T*H int32 = 67.1 MB

    xp_kernel<<<XP_GRID, 256, 0, stream>>>(x, W_ih, b_ih, b_hh, xq);
    rnn_kernel<<<B_ / BB, 512, 0, stream>>>(xq, W_hh, W_fc, b_fc, out);
}